// Round 6
// baseline (361.896 us; speedup 1.0000x reference)
//
#include <hip/hip_runtime.h>

#define N_NODES 50000
#define N_EDGES 800000
#define D_FEAT 32
#define NUM_GRAPHS 64
#define FEATS 320
#define NBKT (N_NODES / 4)              // 12500 dst-buckets of 4 nodes
#define NB2 ((N_NODES + 127) / 128)     // 391 phase-2 blocks of 128 nodes
#define NPART 8                          // XCD partitions
#define PART_NODES ((N_NODES + NPART - 1) / NPART)  // 6250
#define DBINS 64                         // degree-sort bins

// bf16 helpers (RNE pack, shift unpack) — values finite, no NaN path needed
__device__ __forceinline__ unsigned short f2bf(float f) {
    unsigned int u = __float_as_uint(f);
    u = (u + 0x7fffu + ((u >> 16) & 1u)) >> 16;
    return (unsigned short)u;
}
__device__ __forceinline__ float bf2f(unsigned short h) {
    return __uint_as_float((unsigned int)h << 16);
}
__device__ __forceinline__ unsigned int packbf2(float lo, float hi) {
    return (unsigned int)f2bf(lo) | ((unsigned int)f2bf(hi) << 16);
}
__device__ __forceinline__ void acc8(float* a, uint4 v, float w) {
    a[0] += __uint_as_float(v.x << 16) * w;
    a[1] += __uint_as_float(v.x & 0xffff0000u) * w;
    a[2] += __uint_as_float(v.y << 16) * w;
    a[3] += __uint_as_float(v.y & 0xffff0000u) * w;
    a[4] += __uint_as_float(v.z << 16) * w;
    a[5] += __uint_as_float(v.z & 0xffff0000u) * w;
    a[6] += __uint_as_float(v.w << 16) * w;
    a[7] += __uint_as_float(v.w & 0xffff0000u) * w;
}

// ---------------- CSR construction ----------------

__global__ void hist_kernel(const int* __restrict__ dst, int* __restrict__ deg, int n) {
    int e = blockIdx.x * blockDim.x + threadIdx.x;
    if (e < n) atomicAdd(&deg[dst[e]], 1);
}

__global__ void scan1_kernel(const int* __restrict__ deg, int* __restrict__ inc,
                             int* __restrict__ blksum, int n) {
    __shared__ int s[1024];
    int t = threadIdx.x;
    int i = blockIdx.x * 1024 + t;
    int v = (i < n) ? deg[i] : 0;
    s[t] = v;
    __syncthreads();
    for (int off = 1; off < 1024; off <<= 1) {
        int u = (t >= off) ? s[t - off] : 0;
        __syncthreads();
        s[t] += u;
        __syncthreads();
    }
    if (i < n) inc[i] = s[t];
    if (t == 1023) blksum[blockIdx.x] = s[1023];
}

__global__ void scan2_kernel(const int* __restrict__ blksum, int* __restrict__ blkoff, int nblk) {
    __shared__ int s[64];
    int t = threadIdx.x;
    int v = (t < nblk) ? blksum[t] : 0;
    s[t] = v;
    __syncthreads();
    for (int off = 1; off < 64; off <<= 1) {
        int u = (t >= off) ? s[t - off] : 0;
        __syncthreads();
        s[t] += u;
        __syncthreads();
    }
    if (t < nblk) blkoff[t] = s[t] - v;   // exclusive
}

__global__ void scan3_kernel(const int* __restrict__ deg, const int* __restrict__ inc,
                             const int* __restrict__ blkoff, int* __restrict__ rowptr,
                             int* __restrict__ bktcur, int n, int nedges) {
    int i = blockIdx.x * blockDim.x + threadIdx.x;
    if (i < n) {
        int ex = inc[i] - deg[i] + blkoff[i >> 10];
        rowptr[i] = ex;
        if ((i & 3) == 0) bktcur[i >> 2] = ex;   // bucket region start (4 nodes/bucket)
    }
    if (i == 0) rowptr[n] = nedges;
}

// phase 1: XCD-partitioned bucket scatter. Partition p (blockIdx&7, matching
// round-robin XCD dispatch) handles only dst in [p*6250,(p+1)*6250) -> each tmp
// region written by ONE XCD -> lines stay L2-resident until fully packed
// (round-5 lesson: exclusivity, not region size, kills write amplification).
__global__ void scatter1_kernel(const int* __restrict__ src, const int* __restrict__ dst,
                                const float* __restrict__ w, int* __restrict__ bktcur,
                                int2* __restrict__ tmp, int n) {
    int part = blockIdx.x & 7;
    int chunk = blockIdx.x >> 3;
    int nchunks = gridDim.x >> 3;
    int lo = part * PART_NODES, hi = lo + PART_NODES;
    int stride = nchunks * blockDim.x;
    for (int e = chunk * blockDim.x + threadIdx.x; e < n; e += stride) {
        int d = dst[e];
        if (d >= lo && d < hi) {
            int pos = atomicAdd(&bktcur[d >> 2], 1);
            tmp[pos] = make_int2(src[e] | ((d & 127) << 16), __float_as_int(w[e]));
        }
    }
}

// phase 2: one block per 128 nodes (32 buckets); LDS cursors place edges at
// exact CSR offsets. Writes confined to this block's exclusive CSR range.
__global__ void scatter2_kernel(const int* __restrict__ rowptr, const int2* __restrict__ tmp,
                                int2* __restrict__ edges, int n) {
    __shared__ int rp[129];
    __shared__ int cur[128];
    int b = blockIdx.x;
    int node0 = b << 7;
    int nloc = min(128, n - node0);
    int t = threadIdx.x;
    if (t <= 128) rp[t] = rowptr[min(node0 + t, n)];
    if (t < 128) cur[t] = 0;
    __syncthreads();
    int e0 = rp[0], e1 = rp[nloc];
    for (int e = e0 + t; e < e1; e += blockDim.x) {
        int2 p = tmp[e];
        int dl = (p.x >> 16) & 127;
        int pos = rp[dl] + atomicAdd(&cur[dl], 1);
        edges[pos] = make_int2(p.x & 0xffff, p.y);
    }
}

// ---------------- degree sort (counting sort, block-aggregated) ----------------
// perm2[slot] = (rowptr[i], node | deg<<16), slots grouped by degree ->
// degree-uniform waves in spmm (no max-degree divergence waste).

__global__ void dhist_kernel(const int* __restrict__ deg, int* __restrict__ gbins,
                             int chunk, int n) {
    __shared__ int h[DBINS];
    int t = threadIdx.x;
    if (t < DBINS) h[t] = 0;
    __syncthreads();
    int start = blockIdx.x * chunk, end = min(start + chunk, n);
    for (int i = start + t; i < end; i += blockDim.x)
        atomicAdd(&h[min(deg[i], DBINS - 1)], 1);
    __syncthreads();
    if (t < DBINS && h[t]) atomicAdd(&gbins[t], h[t]);
}

__global__ void dscan_kernel(const int* __restrict__ gbins, int* __restrict__ gcur) {
    __shared__ int s[DBINS];
    int t = threadIdx.x;
    int v = gbins[t];
    s[t] = v;
    __syncthreads();
    for (int off = 1; off < DBINS; off <<= 1) {
        int u = (t >= off) ? s[t - off] : 0;
        __syncthreads();
        s[t] += u;
        __syncthreads();
    }
    gcur[t] = s[t] - v;   // exclusive
}

__global__ void dscatter_kernel(const int* __restrict__ deg, const int* __restrict__ rowptr,
                                int* __restrict__ gcur, int2* __restrict__ perm2,
                                int chunk, int n) {
    __shared__ int h[DBINS], base[DBINS], cur[DBINS];
    int t = threadIdx.x;
    if (t < DBINS) h[t] = 0;
    __syncthreads();
    int start = blockIdx.x * chunk, end = min(start + chunk, n);
    for (int i = start + t; i < end; i += blockDim.x)
        atomicAdd(&h[min(deg[i], DBINS - 1)], 1);
    __syncthreads();
    if (t < DBINS) {
        base[t] = h[t] ? atomicAdd(&gcur[t], h[t]) : 0;
        cur[t] = 0;
    }
    __syncthreads();
    for (int i = start + t; i < end; i += blockDim.x) {
        int d = deg[i];
        int b = min(d, DBINS - 1);
        int loc = atomicAdd(&cur[b], 1);
        perm2[base[b] + loc] = make_int2(rowptr[i], i | (d << 16));
    }
}

// ---------------- X -> bf16 conversion ----------------

__global__ void cvt_kernel(const float4* __restrict__ xin, ushort4* __restrict__ xout, int n4) {
    int i = blockIdx.x * blockDim.x + threadIdx.x;
    if (i < n4) {
        float4 v = xin[i];
        ushort4 o;
        o.x = f2bf(v.x); o.y = f2bf(v.y); o.z = f2bf(v.z); o.w = f2bf(v.w);
        xout[i] = o;
    }
}

// ---------------- graph boundaries (batch is sorted) ----------------

__global__ void gbound_kernel(const int* __restrict__ batch, int* __restrict__ gstart, int n) {
    int i = blockIdx.x * blockDim.x + threadIdx.x;
    if (i >= n) return;
    int g = batch[i];
    int gp = (i == 0) ? -1 : batch[i - 1];
    for (int gg = gp + 1; gg <= g; ++gg) gstart[gg] = i;
    if (i == n - 1)
        for (int gg = g + 1; gg <= NUM_GRAPHS; ++gg) gstart[gg] = n;
}

// ---------------- SpMM (pull, no atomics), D=32 bf16 ----------------
// 4 lanes/node, lane owns 8 cols as uint4 (16B = coalescing sweet spot).
// Wave covers 16 nodes of ~equal degree (degree-sorted perm). fp32 accum.

__global__ void spmm_kernel(const uint4* __restrict__ xin,
                            uint4* __restrict__ yout,
                            const int2* __restrict__ perm2,
                            const int2* __restrict__ edges, int n) {
    int lane = threadIdx.x & 3;
    int slot = (blockIdx.x * blockDim.x + threadIdx.x) >> 2;
    if (slot >= n) return;
    int2 pe = perm2[slot];
    int e0 = pe.x;
    int node = pe.y & 0xffff;
    int deg = ((unsigned int)pe.y) >> 16;
    int e1 = e0 + deg;
    float a[8] = {0.f, 0.f, 0.f, 0.f, 0.f, 0.f, 0.f, 0.f};
    int e = e0;
    int e4 = e0 + (deg & ~3);
    for (; e < e4; e += 4) {
        int2 p0 = edges[e + 0];
        int2 p1 = edges[e + 1];
        int2 p2 = edges[e + 2];
        int2 p3 = edges[e + 3];
        uint4 v0 = xin[(size_t)p0.x * 4 + lane];
        uint4 v1 = xin[(size_t)p1.x * 4 + lane];
        uint4 v2 = xin[(size_t)p2.x * 4 + lane];
        uint4 v3 = xin[(size_t)p3.x * 4 + lane];
        acc8(a, v0, __int_as_float(p0.y));
        acc8(a, v1, __int_as_float(p1.y));
        acc8(a, v2, __int_as_float(p2.y));
        acc8(a, v3, __int_as_float(p3.y));
    }
    for (; e < e1; ++e) {
        int2 p = edges[e];
        uint4 v = xin[(size_t)p.x * 4 + lane];
        acc8(a, v, __int_as_float(p.y));
    }
    uint4 o;
    o.x = packbf2(a[0], a[1]);
    o.y = packbf2(a[2], a[3]);
    o.z = packbf2(a[4], a[5]);
    o.w = packbf2(a[6], a[7]);
    yout[(size_t)node * 4 + lane] = o;
}

// ---------------- fused pooling: 10 terms, 64 graphs x 16 slices ----------------

struct PoolArgs10 {
    const unsigned short* P[10];
    const unsigned short* Q[10];
};

__global__ __launch_bounds__(320) void pool_kernel(PoolArgs10 a, const int* __restrict__ gstart,
                                                   float* __restrict__ out) {
    int k = threadIdx.x >> 5;
    int f = threadIdx.x & 31;
    int g = blockIdx.x >> 4;
    int s = blockIdx.x & 15;
    int gs = gstart[g], ge = gstart[g + 1];
    int len = ge - gs;
    int i0 = gs + ((len * s) >> 4);
    int i1 = gs + ((len * (s + 1)) >> 4);
    const unsigned short* __restrict__ P = a.P[k];
    const unsigned short* __restrict__ Q = a.Q[k];
    float acc = 0.f;
    if (Q) {
        for (int i = i0; i < i1; ++i)
            acc += fabsf(bf2f(P[(size_t)i * 32 + f]) - bf2f(Q[(size_t)i * 32 + f]));
    } else {
        for (int i = i0; i < i1; ++i)
            acc += bf2f(P[(size_t)i * 32 + f]);
    }
    if (i1 > i0) atomicAdd(&out[g * FEATS + k * 32 + f], acc);
}

__global__ void divide_kernel(float* __restrict__ out, const int* __restrict__ gstart, int total) {
    int i = blockIdx.x * blockDim.x + threadIdx.x;
    if (i < total) {
        int g = i / FEATS;
        float c = (float)(gstart[g + 1] - gstart[g]);
        out[i] /= fmaxf(c, 1.0f);
    }
}

// ---------------- host launch ----------------

extern "C" void kernel_launch(void* const* d_in, const int* in_sizes, int n_in,
                              void* d_out, int out_size, void* d_ws, size_t ws_size,
                              hipStream_t stream) {
    const float* X     = (const float*)d_in[0];
    const int*   ei    = (const int*)d_in[1];
    const float* ew    = (const float*)d_in[2];
    const int*   batch = (const int*)d_in[3];
    float* out = (float*)d_out;

    const int N = N_NODES, E = N_EDGES;
    const int* src = ei;
    const int* dst = ei + E;

    char* base = (char*)d_ws;
    size_t off = 0;
    auto alloc = [&](size_t bytes) -> void* {
        void* p = base + off;
        off += (bytes + 255) & ~(size_t)255;
        return p;
    };
    // bf16 diffusion chain buffers y[k] = P^k X, k=0..12 (y[0] = bf16(X))
    unsigned short* y[13];
    for (int k = 0; k <= 12; ++k) y[k] = (unsigned short*)alloc((size_t)N * 32 * 2);

    int*  deg    = (int*)alloc((size_t)N * 4);
    int*  inc    = (int*)alloc((size_t)N * 4);
    int*  rowptr = (int*)alloc((size_t)(N + 4) * 4);
    int*  bktcur = (int*)alloc((size_t)(NBKT + 4) * 4);
    int*  blksum = (int*)alloc(64 * 4);
    int*  blkoff = (int*)alloc(64 * 4);
    int*  gstart = (int*)alloc((NUM_GRAPHS + 1) * 4);
    int*  gbins  = (int*)alloc(DBINS * 4);
    int*  gcur   = (int*)alloc(DBINS * 4);
    int2* perm2  = (int2*)alloc((size_t)N * 8);
    int2* tmp    = (int2*)alloc((size_t)E * 8);
    int2* edges  = (int2*)alloc((size_t)E * 8);

    hipMemsetAsync(deg, 0, (size_t)N * 4, stream);
    hipMemsetAsync(out, 0, (size_t)out_size * 4, stream);
    hipMemsetAsync(gbins, 0, DBINS * 4, stream);

    // CSR by dst (XCD-partitioned two-phase scatter)
    hist_kernel<<<(E + 255) / 256, 256, 0, stream>>>(dst, deg, E);
    const int NBLK = (N + 1023) / 1024; // 49
    scan1_kernel<<<NBLK, 1024, 0, stream>>>(deg, inc, blksum, N);
    scan2_kernel<<<1, 64, 0, stream>>>(blksum, blkoff, NBLK);
    scan3_kernel<<<(N + 255) / 256, 256, 0, stream>>>(deg, inc, blkoff, rowptr, bktcur, N, E);
    scatter1_kernel<<<8 * 392, 256, 0, stream>>>(src, dst, ew, bktcur, tmp, E);
    scatter2_kernel<<<NB2, 256, 0, stream>>>(rowptr, tmp, edges, N);

    // degree sort -> perm2 (degree-uniform waves in spmm)
    const int DCHUNK = (N + 15) / 16;  // 16 blocks: <=16 same-address atomics per bin
    dhist_kernel<<<16, 1024, 0, stream>>>(deg, gbins, DCHUNK, N);
    dscan_kernel<<<1, DBINS, 0, stream>>>(gbins, gcur);
    dscatter_kernel<<<16, 1024, 0, stream>>>(deg, rowptr, gcur, perm2, DCHUNK, N);

    // X -> bf16; graph boundaries
    cvt_kernel<<<(N * 32 / 4 + 255) / 256, 256, 0, stream>>>((const float4*)X, (ushort4*)y[0],
                                                             N * 32 / 4);
    gbound_kernel<<<(N + 255) / 256, 256, 0, stream>>>(batch, gstart, N);

    // ---- single D=32 bf16 diffusion chain: y[k] = P y[k-1], k = 1..12
    const int SPMM_GRID = (N * 4 + 255) / 256;  // 782 blocks, 64 nodes/block
    for (int k = 1; k <= 12; ++k) {
        spmm_kernel<<<SPMM_GRID, 256, 0, stream>>>((const uint4*)y[k - 1], (uint4*)y[k],
                                                   perm2, edges, N);
    }

    // ---- fused pooling of all 10 feature column-blocks
    // F0 = y8 | F1: |y1-y2|, |y2-y4|, |y4-y8|
    // F2 (ref order): |y3-y2|, |y5-y3|, |y9-y5|, |y6-y4|, |y10-y6|, |y12-y8|
    {
        PoolArgs10 p{};
        const unsigned short* Ps[10] = {y[8], y[1], y[2], y[4], y[3], y[5], y[9], y[6], y[10], y[12]};
        const unsigned short* Qs[10] = {nullptr, y[2], y[4], y[8], y[2], y[3], y[5], y[4], y[6], y[8]};
        for (int k = 0; k < 10; ++k) { p.P[k] = Ps[k]; p.Q[k] = Qs[k]; }
        pool_kernel<<<NUM_GRAPHS * 16, 320, 0, stream>>>(p, gstart, out);
    }

    divide_kernel<<<(out_size + 255) / 256, 256, 0, stream>>>(out, gstart, out_size);
}

// Round 7
// 317.615 us; speedup vs baseline: 1.1394x; 1.1394x over previous
//
#include <hip/hip_runtime.h>

#define N_NODES 50000
#define N_EDGES 800000
#define D_FEAT 32
#define NUM_GRAPHS 64
#define FEATS 320
#define NBIN 128                         // bins of 512 nodes (98 used)
#define BINSH 9
#define CE 4096                          // edges per binning chunk
#define NCHUNK ((N_EDGES + CE - 1) / CE) // 196
#define NPB ((N_NODES + 511) / 512)      // 98 place blocks

// bf16 helpers (RNE pack, shift unpack) — values finite, no NaN path needed
__device__ __forceinline__ unsigned short f2bf(float f) {
    unsigned int u = __float_as_uint(f);
    u = (u + 0x7fffu + ((u >> 16) & 1u)) >> 16;
    return (unsigned short)u;
}
__device__ __forceinline__ float bf2f(unsigned short h) {
    return __uint_as_float((unsigned int)h << 16);
}

// ---------------- degree histogram + rowptr scan ----------------

__global__ void hist_kernel(const int* __restrict__ dst, int* __restrict__ deg, int n) {
    int e = blockIdx.x * blockDim.x + threadIdx.x;
    if (e < n) atomicAdd(&deg[dst[e]], 1);
}

__global__ void scan1_kernel(const int* __restrict__ deg, int* __restrict__ inc,
                             int* __restrict__ blksum, int n) {
    __shared__ int s[1024];
    int t = threadIdx.x;
    int i = blockIdx.x * 1024 + t;
    int v = (i < n) ? deg[i] : 0;
    s[t] = v;
    __syncthreads();
    for (int off = 1; off < 1024; off <<= 1) {
        int u = (t >= off) ? s[t - off] : 0;
        __syncthreads();
        s[t] += u;
        __syncthreads();
    }
    if (i < n) inc[i] = s[t];
    if (t == 1023) blksum[blockIdx.x] = s[1023];
}

__global__ void scan2_kernel(const int* __restrict__ blksum, int* __restrict__ blkoff, int nblk) {
    __shared__ int s[64];
    int t = threadIdx.x;
    int v = (t < nblk) ? blksum[t] : 0;
    s[t] = v;
    __syncthreads();
    for (int off = 1; off < 64; off <<= 1) {
        int u = (t >= off) ? s[t - off] : 0;
        __syncthreads();
        s[t] += u;
        __syncthreads();
    }
    if (t < nblk) blkoff[t] = s[t] - v;   // exclusive
}

__global__ void scan3_kernel(const int* __restrict__ deg, const int* __restrict__ inc,
                             const int* __restrict__ blkoff, int* __restrict__ rowptr,
                             int n, int nedges) {
    int i = blockIdx.x * blockDim.x + threadIdx.x;
    if (i < n) rowptr[i] = inc[i] - deg[i] + blkoff[i >> 10];
    if (i == 0) rowptr[n] = nedges;
}

// ---------------- atomic-free binning sort (3 phases + place) ----------------
// Round-6 lessons: (a) write amplification comes from non-exclusive random 8B
// stores (~64B/line RMW over fabric); (b) same-address global atomics ~330 cyc
// serialized. So: deterministic per-(chunk,bin) bases, coalesced segment writes.

// Phase A: per-chunk histogram over 128 coarse bins -> counts[chunk][bin]
__global__ void binA_kernel(const int* __restrict__ dst, int* __restrict__ counts, int n) {
    __shared__ int h[NBIN];
    int t = threadIdx.x;
    if (t < NBIN) h[t] = 0;
    __syncthreads();
    int s0 = blockIdx.x * CE, e0 = min(s0 + CE, n);
    for (int i = s0 + t; i < e0; i += blockDim.x)
        atomicAdd(&h[dst[i] >> BINSH], 1);
    __syncthreads();
    if (t < NBIN) counts[blockIdx.x * NBIN + t] = h[t];
}

// Phase B: convert counts to exact global base offsets (serial per-bin scan,
// seeded from rowptr[bin*512]). One block, 128 threads, no atomics.
__global__ void binB_kernel(const int* __restrict__ rowptr, int* __restrict__ counts, int n) {
    int bin = threadIdx.x;
    int node0 = bin << BINSH;
    int running = rowptr[min(node0, n)];
    for (int c = 0; c < NCHUNK; ++c) {
        int idx = c * NBIN + bin;
        int v = counts[idx];
        counts[idx] = running;
        running += v;
    }
}

// Phase C: re-hist, LDS-scatter chunk grouped by bin, then coalesced
// contiguous writes to deterministic bases. rec = src | (w_bf16 << 16);
// loc = dst & 511 (position within 512-node bin, for exact placement).
__global__ __launch_bounds__(256) void binC_kernel(const int* __restrict__ src,
                                                   const int* __restrict__ dst,
                                                   const float* __restrict__ w,
                                                   const int* __restrict__ counts,
                                                   int2* __restrict__ tmp, int n) {
    __shared__ int h[NBIN], sc[NBIN], cur[NBIN], gbase[NBIN];
    __shared__ int2 srec[CE];
    __shared__ unsigned char sbin[CE];
    int t = threadIdx.x;
    if (t < NBIN) h[t] = 0;
    __syncthreads();
    int s0 = blockIdx.x * CE, e0 = min(s0 + CE, n);
    int cnt = e0 - s0;
    for (int i = s0 + t; i < e0; i += blockDim.x)
        atomicAdd(&h[dst[i] >> BINSH], 1);
    __syncthreads();
    if (t < NBIN) sc[t] = h[t];
    __syncthreads();
    for (int off = 1; off < NBIN; off <<= 1) {
        int u = (t < NBIN && t >= off) ? sc[t - off] : 0;
        __syncthreads();
        if (t < NBIN) sc[t] += u;   // inclusive; exclusive = sc[b]-h[b]
        __syncthreads();
    }
    if (t < NBIN) {
        cur[t] = 0;
        gbase[t] = counts[blockIdx.x * NBIN + t];
    }
    __syncthreads();
    for (int i = s0 + t; i < e0; i += blockDim.x) {
        int d = dst[i];
        int b = d >> BINSH;
        int pos = (sc[b] - h[b]) + atomicAdd(&cur[b], 1);   // LDS atomic: cheap
        srec[pos] = make_int2(src[i] | ((int)f2bf(w[i]) << 16), d & 511);
        sbin[pos] = (unsigned char)b;
    }
    __syncthreads();
    for (int j = t; j < cnt; j += blockDim.x) {
        int b = sbin[j];
        tmp[gbase[b] + (j - (sc[b] - h[b]))] = srec[j];   // coalesced runs per bin
    }
}

// Place: one block per 512-node bin; LDS cursors -> exact CSR slots.
// Writes confined to this bin's exclusive ~32KB CSR range; reads contiguous.
__global__ void place_kernel(const int* __restrict__ rowptr, const int2* __restrict__ tmp,
                             unsigned int* __restrict__ edges, int n) {
    __shared__ int rp[513];
    __shared__ int cur[512];
    int node0 = blockIdx.x << BINSH;
    int t = threadIdx.x;
    for (int i = t; i <= 512; i += blockDim.x) rp[i] = rowptr[min(node0 + i, n)];
    for (int i = t; i < 512; i += blockDim.x) cur[i] = 0;
    __syncthreads();
    int e0 = rp[0], e1 = rp[512];
    for (int e = e0 + t; e < e1; e += blockDim.x) {
        int2 p = tmp[e];
        int pos = rp[p.y] + atomicAdd(&cur[p.y], 1);
        edges[pos] = (unsigned int)p.x;
    }
}

// ---------------- X -> bf16 conversion ----------------

__global__ void cvt_kernel(const float4* __restrict__ xin, ushort4* __restrict__ xout, int n4) {
    int i = blockIdx.x * blockDim.x + threadIdx.x;
    if (i < n4) {
        float4 v = xin[i];
        ushort4 o;
        o.x = f2bf(v.x); o.y = f2bf(v.y); o.z = f2bf(v.z); o.w = f2bf(v.w);
        xout[i] = o;
    }
}

// ---------------- graph boundaries (batch is sorted) ----------------

__global__ void gbound_kernel(const int* __restrict__ batch, int* __restrict__ gstart, int n) {
    int i = blockIdx.x * blockDim.x + threadIdx.x;
    if (i >= n) return;
    int g = batch[i];
    int gp = (i == 0) ? -1 : batch[i - 1];
    for (int gg = gp + 1; gg <= g; ++gg) gstart[gg] = i;
    if (i == n - 1)
        for (int gg = g + 1; gg <= NUM_GRAPHS; ++gg) gstart[gg] = n;
}

// ---------------- SpMM (pull, no atomics), D=32 bf16, 4B edge recs ----------------
// 8 lanes/node; lane owns cols 4l..4l+3 (ushort4, 8B). fp32 accum, bf16 store.

__global__ void spmm_kernel(const ushort4* __restrict__ xin,
                            ushort4* __restrict__ yout,
                            const int* __restrict__ rowptr,
                            const unsigned int* __restrict__ edges, int n) {
    int lane = threadIdx.x & 7;
    int node = (blockIdx.x * blockDim.x + threadIdx.x) >> 3;
    if (node >= n) return;
    int e0 = rowptr[node], e1 = rowptr[node + 1];
    float a0 = 0.f, a1 = 0.f, a2 = 0.f, a3 = 0.f;
    int e = e0;
    int e4 = e0 + ((e1 - e0) & ~3);
    for (; e < e4; e += 4) {
        unsigned int r0 = edges[e + 0];
        unsigned int r1 = edges[e + 1];
        unsigned int r2 = edges[e + 2];
        unsigned int r3 = edges[e + 3];
        ushort4 v0 = xin[(size_t)(r0 & 0xffff) * 8 + lane];
        ushort4 v1 = xin[(size_t)(r1 & 0xffff) * 8 + lane];
        ushort4 v2 = xin[(size_t)(r2 & 0xffff) * 8 + lane];
        ushort4 v3 = xin[(size_t)(r3 & 0xffff) * 8 + lane];
        float w0 = bf2f((unsigned short)(r0 >> 16));
        float w1 = bf2f((unsigned short)(r1 >> 16));
        float w2 = bf2f((unsigned short)(r2 >> 16));
        float w3 = bf2f((unsigned short)(r3 >> 16));
        a0 += bf2f(v0.x) * w0; a1 += bf2f(v0.y) * w0; a2 += bf2f(v0.z) * w0; a3 += bf2f(v0.w) * w0;
        a0 += bf2f(v1.x) * w1; a1 += bf2f(v1.y) * w1; a2 += bf2f(v1.z) * w1; a3 += bf2f(v1.w) * w1;
        a0 += bf2f(v2.x) * w2; a1 += bf2f(v2.y) * w2; a2 += bf2f(v2.z) * w2; a3 += bf2f(v2.w) * w2;
        a0 += bf2f(v3.x) * w3; a1 += bf2f(v3.y) * w3; a2 += bf2f(v3.z) * w3; a3 += bf2f(v3.w) * w3;
    }
    for (; e < e1; ++e) {
        unsigned int r = edges[e];
        ushort4 v = xin[(size_t)(r & 0xffff) * 8 + lane];
        float w = bf2f((unsigned short)(r >> 16));
        a0 += bf2f(v.x) * w; a1 += bf2f(v.y) * w; a2 += bf2f(v.z) * w; a3 += bf2f(v.w) * w;
    }
    yout[(size_t)node * 8 + lane] = make_ushort4(f2bf(a0), f2bf(a1), f2bf(a2), f2bf(a3));
}

// ---------------- fused pooling: 10 terms, 64 graphs x 16 slices ----------------

struct PoolArgs10 {
    const unsigned short* P[10];
    const unsigned short* Q[10];
};

__global__ __launch_bounds__(320) void pool_kernel(PoolArgs10 a, const int* __restrict__ gstart,
                                                   float* __restrict__ out) {
    int k = threadIdx.x >> 5;
    int f = threadIdx.x & 31;
    int g = blockIdx.x >> 4;
    int s = blockIdx.x & 15;
    int gs = gstart[g], ge = gstart[g + 1];
    int len = ge - gs;
    int i0 = gs + ((len * s) >> 4);
    int i1 = gs + ((len * (s + 1)) >> 4);
    const unsigned short* __restrict__ P = a.P[k];
    const unsigned short* __restrict__ Q = a.Q[k];
    float acc = 0.f;
    if (Q) {
        for (int i = i0; i < i1; ++i)
            acc += fabsf(bf2f(P[(size_t)i * 32 + f]) - bf2f(Q[(size_t)i * 32 + f]));
    } else {
        for (int i = i0; i < i1; ++i)
            acc += bf2f(P[(size_t)i * 32 + f]);
    }
    if (i1 > i0) atomicAdd(&out[g * FEATS + k * 32 + f], acc);
}

__global__ void divide_kernel(float* __restrict__ out, const int* __restrict__ gstart, int total) {
    int i = blockIdx.x * blockDim.x + threadIdx.x;
    if (i < total) {
        int g = i / FEATS;
        float c = (float)(gstart[g + 1] - gstart[g]);
        out[i] /= fmaxf(c, 1.0f);
    }
}

// ---------------- host launch ----------------

extern "C" void kernel_launch(void* const* d_in, const int* in_sizes, int n_in,
                              void* d_out, int out_size, void* d_ws, size_t ws_size,
                              hipStream_t stream) {
    const float* X     = (const float*)d_in[0];
    const int*   ei    = (const int*)d_in[1];
    const float* ew    = (const float*)d_in[2];
    const int*   batch = (const int*)d_in[3];
    float* out = (float*)d_out;

    const int N = N_NODES, E = N_EDGES;
    const int* src = ei;
    const int* dst = ei + E;

    char* base = (char*)d_ws;
    size_t off = 0;
    auto alloc = [&](size_t bytes) -> void* {
        void* p = base + off;
        off += (bytes + 255) & ~(size_t)255;
        return p;
    };
    // bf16 diffusion chain buffers y[k] = P^k X, k=0..12 (y[0] = bf16(X))
    unsigned short* y[13];
    for (int k = 0; k <= 12; ++k) y[k] = (unsigned short*)alloc((size_t)N * 32 * 2);

    int*  deg    = (int*)alloc((size_t)N * 4);
    int*  inc    = (int*)alloc((size_t)N * 4);
    int*  rowptr = (int*)alloc((size_t)(N + 4) * 4);
    int*  blksum = (int*)alloc(64 * 4);
    int*  blkoff = (int*)alloc(64 * 4);
    int*  gstart = (int*)alloc((NUM_GRAPHS + 1) * 4);
    int*  counts = (int*)alloc((size_t)NCHUNK * NBIN * 4);
    int2* tmp    = (int2*)alloc((size_t)E * 8);
    unsigned int* edges = (unsigned int*)alloc((size_t)E * 4);

    hipMemsetAsync(deg, 0, (size_t)N * 4, stream);
    hipMemsetAsync(out, 0, (size_t)out_size * 4, stream);

    // rowptr (CSR by dst)
    hist_kernel<<<(E + 255) / 256, 256, 0, stream>>>(dst, deg, E);
    const int NBLK = (N + 1023) / 1024; // 49
    scan1_kernel<<<NBLK, 1024, 0, stream>>>(deg, inc, blksum, N);
    scan2_kernel<<<1, 64, 0, stream>>>(blksum, blkoff, NBLK);
    scan3_kernel<<<(N + 255) / 256, 256, 0, stream>>>(deg, inc, blkoff, rowptr, N, E);

    // atomic-free binning sort -> edges in CSR order (4B records)
    binA_kernel<<<NCHUNK, 256, 0, stream>>>(dst, counts, E);
    binB_kernel<<<1, NBIN, 0, stream>>>(rowptr, counts, N);
    binC_kernel<<<NCHUNK, 256, 0, stream>>>(src, dst, ew, counts, tmp, E);
    place_kernel<<<NPB, 256, 0, stream>>>(rowptr, tmp, edges, N);

    // X -> bf16; graph boundaries
    cvt_kernel<<<(N * 32 / 4 + 255) / 256, 256, 0, stream>>>((const float4*)X, (ushort4*)y[0],
                                                             N * 32 / 4);
    gbound_kernel<<<(N + 255) / 256, 256, 0, stream>>>(batch, gstart, N);

    // ---- single D=32 bf16 diffusion chain: y[k] = P y[k-1], k = 1..12
    const int SPMM_GRID = (N * 8 + 255) / 256;  // 1563 blocks, 32 nodes/block
    for (int k = 1; k <= 12; ++k) {
        spmm_kernel<<<SPMM_GRID, 256, 0, stream>>>((const ushort4*)y[k - 1], (ushort4*)y[k],
                                                   rowptr, edges, N);
    }

    // ---- fused pooling of all 10 feature column-blocks
    // F0 = y8 | F1: |y1-y2|, |y2-y4|, |y4-y8|
    // F2 (ref order): |y3-y2|, |y5-y3|, |y9-y5|, |y6-y4|, |y10-y6|, |y12-y8|
    {
        PoolArgs10 p{};
        const unsigned short* Ps[10] = {y[8], y[1], y[2], y[4], y[3], y[5], y[9], y[6], y[10], y[12]};
        const unsigned short* Qs[10] = {nullptr, y[2], y[4], y[8], y[2], y[3], y[5], y[4], y[6], y[8]};
        for (int k = 0; k < 10; ++k) { p.P[k] = Ps[k]; p.Q[k] = Qs[k]; }
        pool_kernel<<<NUM_GRAPHS * 16, 320, 0, stream>>>(p, gstart, out);
    }

    divide_kernel<<<(out_size + 255) / 256, 256, 0, stream>>>(out, gstart, out_size);
}

// Round 8
// 294.480 us; speedup vs baseline: 1.2289x; 1.0786x over previous
//
#include <hip/hip_runtime.h>

#define N_NODES 50000
#define N_EDGES 800000
#define D_FEAT 32
#define NUM_GRAPHS 64
#define FEATS 320
#define NBIN 128                         // bins of 512 nodes (98 used)
#define BINSH 9
#define CE 4096                          // edges per binning chunk
#define NCHUNK ((N_EDGES + CE - 1) / CE) // 196
#define NPB ((N_NODES + 511) / 512)      // 98 place blocks

// bf16 helpers (RNE pack, shift unpack) — values finite, no NaN path needed
__device__ __forceinline__ unsigned short f2bf(float f) {
    unsigned int u = __float_as_uint(f);
    u = (u + 0x7fffu + ((u >> 16) & 1u)) >> 16;
    return (unsigned short)u;
}
__device__ __forceinline__ float bf2f(unsigned short h) {
    return __uint_as_float((unsigned int)h << 16);
}

// ---------------- atomic-free binning sort ----------------
// counts[chunk][bin] -> binB turns into exact global write positions and bin
// bases (column-sum + scan; no per-node work). place builds rowptr from a
// per-bin LDS histogram. ZERO global atomics in the entire CSR build.

// Phase A: per-chunk histogram over 128 coarse bins
__global__ void binA_kernel(const int* __restrict__ dst, int* __restrict__ counts, int n) {
    __shared__ int h[NBIN];
    int t = threadIdx.x;
    if (t < NBIN) h[t] = 0;
    __syncthreads();
    int s0 = blockIdx.x * CE, e0 = min(s0 + CE, n);
    for (int i = s0 + t; i < e0; i += blockDim.x)
        atomicAdd(&h[dst[i] >> BINSH], 1);
    __syncthreads();
    if (t < NBIN) counts[blockIdx.x * NBIN + t] = h[t];
}

// Phase B: bin totals -> exclusive bin bases; rewrite counts[c][b] to exact
// global positions. One block, 128 threads, unrolled for load MLP.
__global__ void binB_kernel(int* __restrict__ counts, int* __restrict__ binBase) {
    __shared__ int s[NBIN];
    int b = threadIdx.x;
    int tot = 0;
    #pragma unroll 8
    for (int c = 0; c < NCHUNK; ++c) tot += counts[c * NBIN + b];
    s[b] = tot;
    __syncthreads();
    for (int off = 1; off < NBIN; off <<= 1) {
        int u = (b >= off) ? s[b - off] : 0;
        __syncthreads();
        s[b] += u;
        __syncthreads();
    }
    int base = s[b] - tot;   // exclusive
    binBase[b] = base;
    if (b == NBIN - 1) binBase[NBIN] = s[b];
    int running = base;
    #pragma unroll 4
    for (int c = 0; c < NCHUNK; ++c) {
        int idx = c * NBIN + b;
        int v = counts[idx];
        counts[idx] = running;
        running += v;
    }
}

// Phase C: re-hist, LDS-group chunk by bin, coalesced segment writes to
// deterministic global positions. rec = src | (w_bf16 << 16), loc = dst & 511.
__global__ __launch_bounds__(256) void binC_kernel(const int* __restrict__ src,
                                                   const int* __restrict__ dst,
                                                   const float* __restrict__ w,
                                                   const int* __restrict__ counts,
                                                   int2* __restrict__ tmp, int n) {
    __shared__ int h[NBIN], sc[NBIN], cur[NBIN], gbase[NBIN];
    __shared__ int2 srec[CE];
    __shared__ unsigned char sbin[CE];
    int t = threadIdx.x;
    if (t < NBIN) h[t] = 0;
    __syncthreads();
    int s0 = blockIdx.x * CE, e0 = min(s0 + CE, n);
    int cnt = e0 - s0;
    for (int i = s0 + t; i < e0; i += blockDim.x)
        atomicAdd(&h[dst[i] >> BINSH], 1);
    __syncthreads();
    if (t < NBIN) sc[t] = h[t];
    __syncthreads();
    for (int off = 1; off < NBIN; off <<= 1) {
        int u = (t < NBIN && t >= off) ? sc[t - off] : 0;
        __syncthreads();
        if (t < NBIN) sc[t] += u;   // inclusive; exclusive = sc[b]-h[b]
        __syncthreads();
    }
    if (t < NBIN) {
        cur[t] = 0;
        gbase[t] = counts[blockIdx.x * NBIN + t];
    }
    __syncthreads();
    for (int i = s0 + t; i < e0; i += blockDim.x) {
        int d = dst[i];
        int b = d >> BINSH;
        int pos = (sc[b] - h[b]) + atomicAdd(&cur[b], 1);   // LDS atomic: cheap
        srec[pos] = make_int2(src[i] | ((int)f2bf(w[i]) << 16), d & 511);
        sbin[pos] = (unsigned char)b;
    }
    __syncthreads();
    for (int j = t; j < cnt; j += blockDim.x) {
        int b = sbin[j];
        tmp[gbase[b] + (j - (sc[b] - h[b]))] = srec[j];   // coalesced runs per bin
    }
}

// Place: one block per 512-node bin. LDS 512-histogram + scan builds rowptr
// for this bin (coalesced write) and places edges at exact CSR slots within
// the bin's exclusive ~32KB region.
__global__ __launch_bounds__(256) void place_kernel(const int* __restrict__ binBase,
                                                    const int2* __restrict__ tmp,
                                                    unsigned int* __restrict__ edges,
                                                    int* __restrict__ rowptr, int n) {
    __shared__ int h[512], sc[512], cur[512];
    int b = blockIdx.x;
    int t = threadIdx.x;
    int base = binBase[b], end = binBase[b + 1];
    for (int i = t; i < 512; i += 256) { h[i] = 0; cur[i] = 0; }
    __syncthreads();
    for (int e = base + t; e < end; e += 256)
        atomicAdd(&h[tmp[e].y], 1);
    __syncthreads();
    for (int i = t; i < 512; i += 256) sc[i] = h[i];
    __syncthreads();
    // Hillis-Steele over 512 with 256 threads (read-all before write-all)
    for (int off = 1; off < 512; off <<= 1) {
        int i0 = t, i1 = t + 256;
        int a0 = (i0 >= off) ? sc[i0 - off] : 0;
        int a1 = (i1 >= off) ? sc[i1 - off] : 0;
        __syncthreads();
        sc[i0] += a0;
        sc[i1] += a1;
        __syncthreads();
    }
    int node0 = b << BINSH;
    for (int i = t; i < 512; i += 256) {
        int node = node0 + i;
        if (node <= n) rowptr[node] = base + sc[i] - h[i];   // exclusive
    }
    if (b == 0 && t == 0) rowptr[0] = 0;
    __syncthreads();
    for (int e = base + t; e < end; e += 256) {
        int2 p = tmp[e];
        int loc = p.y;
        int pos = base + (sc[loc] - h[loc]) + atomicAdd(&cur[loc], 1);
        edges[pos] = (unsigned int)p.x;
    }
}

// ---------------- X -> bf16 conversion ----------------

__global__ void cvt_kernel(const float4* __restrict__ xin, ushort4* __restrict__ xout, int n4) {
    int i = blockIdx.x * blockDim.x + threadIdx.x;
    if (i < n4) {
        float4 v = xin[i];
        ushort4 o;
        o.x = f2bf(v.x); o.y = f2bf(v.y); o.z = f2bf(v.z); o.w = f2bf(v.w);
        xout[i] = o;
    }
}

// ---------------- graph boundaries (batch is sorted) ----------------

__global__ void gbound_kernel(const int* __restrict__ batch, int* __restrict__ gstart, int n) {
    int i = blockIdx.x * blockDim.x + threadIdx.x;
    if (i >= n) return;
    int g = batch[i];
    int gp = (i == 0) ? -1 : batch[i - 1];
    for (int gg = gp + 1; gg <= g; ++gg) gstart[gg] = i;
    if (i == n - 1)
        for (int gg = g + 1; gg <= NUM_GRAPHS; ++gg) gstart[gg] = n;
}

// ---------------- SpMM (pull, no atomics), D=32 bf16, 4B edge recs ----------------
// 8 lanes/node; lane owns cols 4l..4l+3 (ushort4). UNROLL 8: 8 gather instrs
// x 8 rows each = 64 lines in flight per wave (2x round 7) — concurrency vs
// fabric-ceiling A/B test. fp32 accum, bf16 store.

__global__ __launch_bounds__(256) void spmm_kernel(const ushort4* __restrict__ xin,
                                                   ushort4* __restrict__ yout,
                                                   const int* __restrict__ rowptr,
                                                   const unsigned int* __restrict__ edges,
                                                   int n) {
    int lane = threadIdx.x & 7;
    int node = (blockIdx.x * blockDim.x + threadIdx.x) >> 3;
    if (node >= n) return;
    int e0 = rowptr[node], e1 = rowptr[node + 1];
    float a0 = 0.f, a1 = 0.f, a2 = 0.f, a3 = 0.f;
    int e = e0;
    int e8 = e0 + ((e1 - e0) & ~7);
    for (; e < e8; e += 8) {
        unsigned int r[8];
        #pragma unroll
        for (int u = 0; u < 8; ++u) r[u] = edges[e + u];
        ushort4 v[8];
        #pragma unroll
        for (int u = 0; u < 8; ++u)
            v[u] = xin[(size_t)(r[u] & 0xffff) * 8 + lane];
        #pragma unroll
        for (int u = 0; u < 8; ++u) {
            float w = bf2f((unsigned short)(r[u] >> 16));
            a0 += bf2f(v[u].x) * w;
            a1 += bf2f(v[u].y) * w;
            a2 += bf2f(v[u].z) * w;
            a3 += bf2f(v[u].w) * w;
        }
    }
    for (; e < e1; ++e) {
        unsigned int r = edges[e];
        ushort4 v = xin[(size_t)(r & 0xffff) * 8 + lane];
        float w = bf2f((unsigned short)(r >> 16));
        a0 += bf2f(v.x) * w; a1 += bf2f(v.y) * w; a2 += bf2f(v.z) * w; a3 += bf2f(v.w) * w;
    }
    yout[(size_t)node * 8 + lane] = make_ushort4(f2bf(a0), f2bf(a1), f2bf(a2), f2bf(a3));
}

// ---------------- fused pooling: 10 terms, 64 graphs x 16 slices ----------------

struct PoolArgs10 {
    const unsigned short* P[10];
    const unsigned short* Q[10];
};

__global__ __launch_bounds__(320) void pool_kernel(PoolArgs10 a, const int* __restrict__ gstart,
                                                   float* __restrict__ out) {
    int k = threadIdx.x >> 5;
    int f = threadIdx.x & 31;
    int g = blockIdx.x >> 4;
    int s = blockIdx.x & 15;
    int gs = gstart[g], ge = gstart[g + 1];
    int len = ge - gs;
    int i0 = gs + ((len * s) >> 4);
    int i1 = gs + ((len * (s + 1)) >> 4);
    const unsigned short* __restrict__ P = a.P[k];
    const unsigned short* __restrict__ Q = a.Q[k];
    float acc = 0.f;
    if (Q) {
        for (int i = i0; i < i1; ++i)
            acc += fabsf(bf2f(P[(size_t)i * 32 + f]) - bf2f(Q[(size_t)i * 32 + f]));
    } else {
        for (int i = i0; i < i1; ++i)
            acc += bf2f(P[(size_t)i * 32 + f]);
    }
    if (i1 > i0) atomicAdd(&out[g * FEATS + k * 32 + f], acc);
}

__global__ void divide_kernel(float* __restrict__ out, const int* __restrict__ gstart, int total) {
    int i = blockIdx.x * blockDim.x + threadIdx.x;
    if (i < total) {
        int g = i / FEATS;
        float c = (float)(gstart[g + 1] - gstart[g]);
        out[i] /= fmaxf(c, 1.0f);
    }
}

// ---------------- host launch ----------------

extern "C" void kernel_launch(void* const* d_in, const int* in_sizes, int n_in,
                              void* d_out, int out_size, void* d_ws, size_t ws_size,
                              hipStream_t stream) {
    const float* X     = (const float*)d_in[0];
    const int*   ei    = (const int*)d_in[1];
    const float* ew    = (const float*)d_in[2];
    const int*   batch = (const int*)d_in[3];
    float* out = (float*)d_out;

    const int N = N_NODES, E = N_EDGES;
    const int* src = ei;
    const int* dst = ei + E;

    char* base = (char*)d_ws;
    size_t off = 0;
    auto alloc = [&](size_t bytes) -> void* {
        void* p = base + off;
        off += (bytes + 255) & ~(size_t)255;
        return p;
    };
    // bf16 diffusion chain buffers y[k] = P^k X, k=0..12 (y[0] = bf16(X))
    unsigned short* y[13];
    for (int k = 0; k <= 12; ++k) y[k] = (unsigned short*)alloc((size_t)N * 32 * 2);

    int*  rowptr  = (int*)alloc((size_t)(N + 4) * 4);
    int*  gstart  = (int*)alloc((NUM_GRAPHS + 1) * 4);
    int*  counts  = (int*)alloc((size_t)NCHUNK * NBIN * 4);
    int*  binBase = (int*)alloc((NBIN + 1) * 4);
    int2* tmp     = (int2*)alloc((size_t)E * 8);
    unsigned int* edges = (unsigned int*)alloc((size_t)E * 4);

    hipMemsetAsync(out, 0, (size_t)out_size * 4, stream);

    // atomic-free CSR build: counts -> positions -> grouped tmp -> edges+rowptr
    binA_kernel<<<NCHUNK, 256, 0, stream>>>(dst, counts, E);
    binB_kernel<<<1, NBIN, 0, stream>>>(counts, binBase);
    binC_kernel<<<NCHUNK, 256, 0, stream>>>(src, dst, ew, counts, tmp, E);
    place_kernel<<<NPB, 256, 0, stream>>>(binBase, tmp, edges, rowptr, N);

    // X -> bf16; graph boundaries
    cvt_kernel<<<(N * 32 / 4 + 255) / 256, 256, 0, stream>>>((const float4*)X, (ushort4*)y[0],
                                                             N * 32 / 4);
    gbound_kernel<<<(N + 255) / 256, 256, 0, stream>>>(batch, gstart, N);

    // ---- single D=32 bf16 diffusion chain: y[k] = P y[k-1], k = 1..12
    const int SPMM_GRID = (N * 8 + 255) / 256;  // 1563 blocks, 32 nodes/block
    for (int k = 1; k <= 12; ++k) {
        spmm_kernel<<<SPMM_GRID, 256, 0, stream>>>((const ushort4*)y[k - 1], (ushort4*)y[k],
                                                   rowptr, edges, N);
    }

    // ---- fused pooling of all 10 feature column-blocks
    // F0 = y8 | F1: |y1-y2|, |y2-y4|, |y4-y8|
    // F2 (ref order): |y3-y2|, |y5-y3|, |y9-y5|, |y6-y4|, |y10-y6|, |y12-y8|
    {
        PoolArgs10 p{};
        const unsigned short* Ps[10] = {y[8], y[1], y[2], y[4], y[3], y[5], y[9], y[6], y[10], y[12]};
        const unsigned short* Qs[10] = {nullptr, y[2], y[4], y[8], y[2], y[3], y[5], y[4], y[6], y[8]};
        for (int k = 0; k < 10; ++k) { p.P[k] = Ps[k]; p.Q[k] = Qs[k]; }
        pool_kernel<<<NUM_GRAPHS * 16, 320, 0, stream>>>(p, gstart, out);
    }

    divide_kernel<<<(out_size + 255) / 256, 256, 0, stream>>>(out, gstart, out_size);
}